// Round 16
// baseline (150.197 us; speedup 1.0000x reference)
//
#include <hip/hip_runtime.h>
#include <math.h>

namespace {
constexpr int kB = 4, kN = 6, kC = 64, kD = 41, kFH = 16, kFW = 44;
constexpr int kNX0 = 200, kNX1 = 200;
constexpr int kHW  = kFH * kFW;                    // 704
constexpr int kPix = kB * kN * kHW;                // 16896 pixels
constexpr int kPts = kPix * kD;                    // 692736 points
constexpr int kVox = kB * kNX0 * kNX1;             // 160000 voxels
constexpr int kPvElems = kPix * kC;                // 1081344
constexpr int kScanBlks = kVox / 256;              // 625 (exact)
constexpr int kPvtTiles = kPix / 64;               // 264
constexpr int kSmBlks = kPix / 256;                // 66
constexpr int kGeoBlks = kPts / 256;               // 2706 (exact)
constexpr int kFrontBlks = kPvtTiles + kSmBlks + kGeoBlks;   // 3036

// ws carve (kOffCnt 16B-aligned)
constexpr size_t kOffPvT    = 0;
constexpr size_t kSzPvT     = (size_t)kPvElems * 4;          // 4,325,376
constexpr size_t kOffVox    = kOffPvT + kSzPvT;
constexpr size_t kSzVox     = (size_t)kPts * 4;              // 2,770,944
constexpr size_t kOffWgt    = kOffVox + kSzVox;
constexpr size_t kSzWgt     = (size_t)kPts * 4;
constexpr size_t kOffCnt    = kOffWgt + kSzWgt;              // 16B aligned
constexpr size_t kSzCnt     = (size_t)kVox * 4;              // 640,000
constexpr size_t kOffOffs   = kOffCnt + kSzCnt;
constexpr size_t kSzOffs    = 640256;                        // padded
constexpr size_t kOffBSum   = kOffOffs + kSzOffs;
constexpr size_t kSzBSum    = 2560;                          // 625 u32, padded
constexpr size_t kOffSKW    = kOffBSum + kSzBSum;
constexpr size_t kSzSKW     = (size_t)kPts * 8;              // uint2 (pix, wgt-bits)
constexpr size_t kWsNeed    = kOffSKW + kSzSKW + 256;        // ~16.7 MB

constexpr int kZeroVec4 = (int)(kSzCnt / 16);                // 40000 uint4 stores
constexpr int kZeroBlks = (kZeroVec4 + 255) / 256;           // 157
}

__device__ __forceinline__ void inv3x3(const float m[9], float inv[9]) {
    float a = m[0], b = m[1], c = m[2];
    float d = m[3], e = m[4], f = m[5];
    float g = m[6], h = m[7], i = m[8];
    float A =  (e * i - f * h);
    float Bm = -(d * i - f * g);
    float Cm =  (d * h - e * g);
    float det = a * A + b * Bm + c * Cm;
    float r = 1.0f / det;
    inv[0] = A * r;
    inv[1] = -(b * i - c * h) * r;
    inv[2] =  (b * f - c * e) * r;
    inv[3] = Bm * r;
    inv[4] =  (a * i - c * g) * r;
    inv[5] = -(a * f - c * d) * r;
    inv[6] = Cm * r;
    inv[7] = -(a * h - b * g) * r;
    inv[8] =  (a * e - b * d) * r;
}

// geometry for point q -> flat voxel id (or -1)
__device__ __forceinline__ int geo_flat(int q,
                                        const float* __restrict__ rots,
                                        const float* __restrict__ trans,
                                        const float* __restrict__ intrins,
                                        const float* __restrict__ post_rots,
                                        const float* __restrict__ post_trans) {
    const int bn  = q / (kD * kHW);
    const int rem = q - bn * (kD * kHW);
    const int d   = rem / kHW;
    const int hw  = rem - d * kHW;
    const int h   = hw / kFW;
    const int w   = hw - h * kFW;
    const int b   = bn / kN;

    const float* R  = rots       + bn * 9;
    const float* K  = intrins    + bn * 9;
    const float* PR = post_rots  + bn * 9;
    const float* PT = post_trans + bn * 3;
    const float* T  = trans      + bn * 3;

    float Km[9], PRm[9];
#pragma unroll
    for (int i = 0; i < 9; ++i) { Km[i] = K[i]; PRm[i] = PR[i]; }
    float invK[9], invPR[9];
    inv3x3(Km, invK);
    inv3x3(PRm, invPR);
    float M[9];
#pragma unroll
    for (int i = 0; i < 3; ++i)
#pragma unroll
        for (int j = 0; j < 3; ++j)
            M[i * 3 + j] = R[i * 3 + 0] * invK[0 * 3 + j]
                         + R[i * 3 + 1] * invK[1 * 3 + j]
                         + R[i * 3 + 2] * invK[2 * 3 + j];

    const float u  = (float)w * (703.0f / 43.0f);
    const float v  = (float)h * 17.0f;
    const float dv = 4.0f + (float)d;
    const float px = u - PT[0], py = v - PT[1], pz = dv - PT[2];
    const float ax = invPR[0] * px + invPR[1] * py + invPR[2] * pz;
    const float ay = invPR[3] * px + invPR[4] * py + invPR[5] * pz;
    const float az = invPR[6] * px + invPR[7] * py + invPR[8] * pz;
    const float qx = ax * az, qy = ay * az, qz = az;
    const float gx = M[0] * qx + M[1] * qy + M[2] * qz + T[0];
    const float gy = M[3] * qx + M[4] * qy + M[5] * qz + T[1];
    const float gz = M[6] * qx + M[7] * qy + M[8] * qz + T[2];
    const float fx = (gx + 50.0f) / 0.5f;
    const float fy = (gy + 50.0f) / 0.5f;
    const float fz = (gz + 10.0f) / 20.0f;
    const int gix = (int)fx;
    const int giy = (int)fy;
    const int giz = (int)fz;
    if (gix >= 0 && gix < kNX0 && giy >= 0 && giy < kNX1 && giz == 0)
        return (b * kNX0 + gix) * kNX1 + giy;
    return -1;
}

// ---- K-1 "zero": fast coalesced zero of counts ----
__global__ __launch_bounds__(256) void lss_zero(uint4* __restrict__ dst) {
    const int i = blockIdx.x * 256 + threadIdx.x;
    if (i < kZeroVec4) dst[i] = make_uint4(0u, 0u, 0u, 0u);
}

// ---- K0 "front": pvT transpose || per-pixel softmax || per-point geometry ----
__global__ __launch_bounds__(256) void lss_front(
    const float* __restrict__ pv,
    const float* __restrict__ feat_depth,
    const float* __restrict__ rots,
    const float* __restrict__ trans,
    const float* __restrict__ intrins,
    const float* __restrict__ post_rots,
    const float* __restrict__ post_trans,
    float* __restrict__ pvT,
    float* __restrict__ wgtArr,
    int* __restrict__ voxArr,
    unsigned* __restrict__ counts)
{
    __shared__ float t[64][65];
    const int blk = blockIdx.x;
    const int tid = threadIdx.x;

    if (blk < kPvtTiles) {
        // 64pix x 64c LDS transpose; both sides coalesced
        const int pix0 = blk * 64;
        const int bn  = pix0 / kHW;
        const int hw0 = pix0 - bn * kHW;
        const int lane = tid & 63;
        const int wv   = tid >> 6;
        const float* src = pv + (size_t)(bn * kC) * kHW + hw0;
#pragma unroll
        for (int cc = 0; cc < 16; ++cc) {
            const int c = wv * 16 + cc;
            t[c][lane] = src[(size_t)c * kHW + lane];
        }
        __syncthreads();
        float* dst = pvT + (size_t)pix0 * kC;
#pragma unroll
        for (int jj = 0; jj < 16; ++jj) {
            const int j = wv * 16 + jj;
            dst[j * kC + lane] = t[lane][j];
        }
    } else if (blk < kPvtTiles + kSmBlks) {
        // one THREAD per pixel; softmax fully in registers
        const int pix = (blk - kPvtTiles) * 256 + tid;
        const int bn = pix / kHW;
        const int hw = pix - bn * kHW;
        const float* p = feat_depth + (size_t)(bn * kD) * kHW + hw;
        float v[kD];
#pragma unroll
        for (int d = 0; d < kD; ++d) v[d] = p[(size_t)d * kHW];
        float mx = v[0];
#pragma unroll
        for (int d = 1; d < kD; ++d) mx = fmaxf(mx, v[d]);
        float sm = 0.0f;
#pragma unroll
        for (int d = 0; d < kD; ++d) { v[d] = __expf(v[d] - mx); sm += v[d]; }
        const float inv = 1.0f / sm;
        float* o = wgtArr + (size_t)(bn * kD) * kHW + hw;
#pragma unroll
        for (int d = 0; d < kD; ++d) o[(size_t)d * kHW] = v[d] * inv;
    } else {
        // per-POINT geometry -> voxArr + histogram
        const int q = (blk - kPvtTiles - kSmBlks) * 256 + tid;   // 2706 blocks exact
        const int f = geo_flat(q, rots, trans, intrins, post_rots, post_trans);
        if (f >= 0) atomicAdd(&counts[f], 1u);
        voxArr[q] = f;
    }
}

// ---- K1a: block-local exclusive scan (625 x 256); offsets stay BLOCK-LOCAL ----
__global__ __launch_bounds__(256) void lss_scan_a(const unsigned* __restrict__ counts,
                                                  unsigned* __restrict__ offsets,
                                                  unsigned* __restrict__ blockSums) {
    const int i = blockIdx.x * 256 + threadIdx.x;
    const int lane = threadIdx.x & 63;
    const int wv = threadIdx.x >> 6;
    const unsigned c = counts[i];
    unsigned s = c;
#pragma unroll
    for (int o = 1; o < 64; o <<= 1) {
        unsigned v = __shfl_up(s, o);
        if (lane >= o) s += v;
    }
    __shared__ unsigned wsum[4];
    if (lane == 63) wsum[wv] = s;
    __syncthreads();
    unsigned base = 0;
#pragma unroll
    for (int k = 0; k < 3; ++k)
        if (k < wv) base += wsum[k];
    const unsigned incl = s + base;
    offsets[i] = incl - c;                  // block-local exclusive
    if (threadIdx.x == 255) blockSums[blockIdx.x] = incl;
}

// ---- K1b: scan 625 block sums in place -> exclusive block bases ----
__global__ __launch_bounds__(1024) void lss_scan_b(unsigned* __restrict__ blockSums) {
    const int t = threadIdx.x;
    const int lane = t & 63;
    const int wv = t >> 6;
    const unsigned c = (t < kScanBlks) ? blockSums[t] : 0u;
    unsigned s = c;
#pragma unroll
    for (int o = 1; o < 64; o <<= 1) {
        unsigned v = __shfl_up(s, o);
        if (lane >= o) s += v;
    }
    __shared__ unsigned wsum[16];
    if (lane == 63) wsum[wv] = s;
    __syncthreads();
    unsigned base = 0;
#pragma unroll
    for (int k = 0; k < 15; ++k)
        if (k < wv) base += wsum[k];
    if (t < kScanBlks) blockSums[t] = (s + base) - c;   // exclusive base
}

// ---- K2: scatter (pix, wgt) into CSR order; voxArr reloaded.
//      global slot = local cursor + blockSums[f>>8]. ----
__global__ __launch_bounds__(256) void lss_order(const int* __restrict__ voxArr,
                                                 const float* __restrict__ wgtArr,
                                                 unsigned* __restrict__ offsets,
                                                 const unsigned* __restrict__ blockSums,
                                                 uint2* __restrict__ skw) {
    const int q = blockIdx.x * 256 + threadIdx.x;      // 2706 blocks exact
    const int f = voxArr[q];
    if (f >= 0) {
        const unsigned slot = atomicAdd(&offsets[f], 1u) + blockSums[f >> 8];
        const int bn  = q / (kD * kHW);
        const int rem = q - bn * (kD * kHW);
        const int hw  = rem % kHW;
        uint2 u;
        u.x = (unsigned)(bn * kHW + hw);               // pix
        u.y = __float_as_uint(wgtArr[q]);
        skw[slot] = u;
    }
}

// ---- K3: per-tile STREAM gather: each wave walks a contiguous span of the
//      chunk's point stream, batching 8 loads ahead across row boundaries;
//      register accumulator flushed to acc[j][lane] at row transitions. ----
__global__ __launch_bounds__(512) void lss_gather(const float* __restrict__ pvT,
                                                  const unsigned* __restrict__ offsets,
                                                  const unsigned* __restrict__ blockSums,
                                                  const uint2* __restrict__ skw,
                                                  float* __restrict__ out) {
    constexpr int kChunk = 2048;                   // 16 KB staging buffer
    __shared__ float acc[50][65];                  // 13 KB
    __shared__ uint2 sbuf[kChunk];                 // 16 KB
    __shared__ unsigned rowOff[51];
    const int tile = blockIdx.x;                   // b*800 + xi*4 + yt
    const int yt = tile & 3;
    const int xi = (tile >> 2) % kNX0;
    const int b  = tile / (kNX0 * 4);
    const int yi0 = yt * 50;
    const int lane = threadIdx.x & 63;
    const int wave = threadIdx.x >> 6;             // 0..7
    const int flat0 = (b * kNX0 + xi) * kNX1 + yi0;

    for (int e = threadIdx.x; e < 50 * 65; e += 512)
        ((float*)acc)[e] = 0.0f;
    if (threadIdx.x < 51) {
        const int f = flat0 - 1 + (int)threadIdx.x;
        rowOff[threadIdx.x] = (f < 0) ? 0u : (offsets[f] + blockSums[f >> 8]);
    }
    __syncthreads();

    const unsigned seg0 = rowOff[0];
    const unsigned seg1 = rowOff[50];

    for (unsigned cb = seg0; cb < seg1; cb += (unsigned)kChunk) {
        const unsigned ce = min(cb + (unsigned)kChunk, seg1);
        const int n = (int)(ce - cb);
        for (int e = threadIdx.x; e < n; e += 512)
            sbuf[e] = skw[cb + e];
        __syncthreads();

        // wave-contiguous span of the point stream
        const int spanLen = (n + 7) >> 3;          // ceil(n/8)
        int p  = wave * spanLen;
        int pe = min(p + spanLen, n);
        if (p < pe) {
            // binary-search starting row: rowOff[j] <= cb+p < rowOff[j+1]
            const unsigned gp0 = cb + (unsigned)p;
            int lo = 0, hi = 50;
            while (hi - lo > 1) {
                const int mid = (lo + hi) >> 1;
                if (rowOff[mid] <= gp0) lo = mid; else hi = mid;
            }
            int j = lo;
            float a = 0.0f;
            while (p < pe) {
                const int batch = min(8, pe - p);
                uint2 u[8];
                float f[8];
#pragma unroll
                for (int k = 0; k < 8; ++k)
                    if (k < batch) u[k] = sbuf[p + k];
#pragma unroll
                for (int k = 0; k < 8; ++k)
                    if (k < batch)
                        f[k] = pvT[(size_t)((unsigned)__builtin_amdgcn_readfirstlane(u[k].x)) * kC + lane];
#pragma unroll
                for (int k = 0; k < 8; ++k) {
                    if (k < batch) {
                        const unsigned gp = cb + (unsigned)(p + k);
                        while (gp >= rowOff[j + 1]) {       // row transition(s)
                            if (a != 0.0f) atomicAdd(&acc[j][lane], a);
                            a = 0.0f;
                            ++j;
                        }
                        a = fmaf(__uint_as_float(__builtin_amdgcn_readfirstlane(u[k].y)), f[k], a);
                    }
                }
                p += batch;
            }
            if (a != 0.0f) atomicAdd(&acc[j][lane], a);
        }
        __syncthreads();                           // sbuf safe to overwrite
    }
    __syncthreads();

    for (int e = threadIdx.x; e < kC * 50; e += 512) {
        const int c = e / 50, j = e % 50;
        out[((b * kC + c) * (kNX0 * kNX1)) + xi * kNX1 + yi0 + j] = acc[j][c];
    }
}

// ---- fallback: atomic path (used only if ws too small) ----
__global__ __launch_bounds__(256) void lss_scatter_fb(
    const float* __restrict__ feat_depth,
    const float* __restrict__ feat_pv,
    const float* __restrict__ rots,
    const float* __restrict__ trans,
    const float* __restrict__ intrins,
    const float* __restrict__ post_rots,
    const float* __restrict__ post_trans,
    float* __restrict__ out)
{
    const int lane = threadIdx.x & 63;
    const int wave = threadIdx.x >> 6;
    const int pix  = blockIdx.x * 4 + wave;
    const int w  = pix % kFW;
    const int h  = (pix / kFW) % kFH;
    const int bn = pix / kHW;
    const int b  = bn / kN;
    const int pixBase = h * kFW + w;
    float fd = -INFINITY;
    if (lane < kD)
        fd = feat_depth[(bn * kD + lane) * kHW + pixBase];
    float mx = fd;
#pragma unroll
    for (int off = 32; off >= 1; off >>= 1)
        mx = fmaxf(mx, __shfl_xor(mx, off));
    float ex = (lane < kD) ? __expf(fd - mx) : 0.0f;
    float sm = ex;
#pragma unroll
    for (int off = 32; off >= 1; off >>= 1)
        sm += __shfl_xor(sm, off);
    const float wgt = ex / sm;
    int vox = -1;
    if (lane < kD) {
        const int q = (bn * kD + lane) * kHW + pixBase;
        const int f = geo_flat(q, rots, trans, intrins, post_rots, post_trans);
        if (f >= 0) vox = f % (kNX0 * kNX1);
    }
    const float fc = feat_pv[(bn * kC + lane) * kHW + pixBase];
    const int outBase = (b * kC + lane) * (kNX0 * kNX1);
#pragma unroll 1
    for (int d = 0; d < kD; ++d) {
        const int   vd = __shfl(vox, d);
        const float wd = __shfl(wgt, d);
        if (vd >= 0)
            atomicAdd(&out[outBase + vd], wd * fc);
    }
}

extern "C" void kernel_launch(void* const* d_in, const int* in_sizes, int n_in,
                              void* d_out, int out_size, void* d_ws, size_t ws_size,
                              hipStream_t stream) {
    const float* feat_depth = (const float*)d_in[0];
    const float* feat_pv    = (const float*)d_in[1];
    const float* rots       = (const float*)d_in[2];
    const float* trans      = (const float*)d_in[3];
    const float* intrins    = (const float*)d_in[4];
    const float* post_rots  = (const float*)d_in[5];
    const float* post_trans = (const float*)d_in[6];
    float* out = (float*)d_out;

    if (ws_size < kWsNeed) {
        hipMemsetAsync(out, 0, (size_t)out_size * sizeof(float), stream);
        lss_scatter_fb<<<kPix / 4, 256, 0, stream>>>(
            feat_depth, feat_pv, rots, trans, intrins, post_rots, post_trans, out);
        return;
    }

    char* ws = (char*)d_ws;
    float*    pvT      = (float*)   (ws + kOffPvT);
    int*      voxArr   = (int*)     (ws + kOffVox);
    float*    wgtArr   = (float*)   (ws + kOffWgt);
    unsigned* counts   = (unsigned*)(ws + kOffCnt);
    unsigned* offsets  = (unsigned*)(ws + kOffOffs);
    unsigned* blockSums= (unsigned*)(ws + kOffBSum);
    uint2*    skw      = (uint2*)   (ws + kOffSKW);

    lss_zero<<<kZeroBlks, 256, 0, stream>>>((uint4*)(ws + kOffCnt));
    lss_front<<<kFrontBlks, 256, 0, stream>>>(
        feat_pv, feat_depth, rots, trans, intrins, post_rots, post_trans,
        pvT, wgtArr, voxArr, counts);
    lss_scan_a<<<kScanBlks, 256, 0, stream>>>(counts, offsets, blockSums);
    lss_scan_b<<<1, 1024, 0, stream>>>(blockSums);
    lss_order<<<kPts / 256, 256, 0, stream>>>(voxArr, wgtArr, offsets, blockSums, skw);
    lss_gather<<<kB * kNX0 * 4, 512, 0, stream>>>(pvT, offsets, blockSums, skw, out);
}

// Round 18
// 111.572 us; speedup vs baseline: 1.3462x; 1.3462x over previous
//
#include <hip/hip_runtime.h>
#include <math.h>

namespace {
constexpr int kB = 4, kN = 6, kC = 64, kD = 41, kFH = 16, kFW = 44;
constexpr int kNX0 = 200, kNX1 = 200;
constexpr int kHW  = kFH * kFW;                    // 704
constexpr int kPix = kB * kN * kHW;                // 16896 pixels
constexpr int kPts = kPix * kD;                    // 692736 points
constexpr int kVox = kB * kNX0 * kNX1;             // 160000 voxels
constexpr int kPvElems = kPix * kC;                // 1081344
constexpr int kScanBlks = kVox / 256;              // 625 (exact)
constexpr int kPvtTiles = kPix / 64;               // 264
constexpr int kSmBlks = kPix / 256;                // 66
constexpr int kGeoBlks = kPts / 256;               // 2706 (exact)
constexpr int kFrontBlks = kPvtTiles + kSmBlks + kGeoBlks;   // 3036

// ws carve (kOffCnt 16B-aligned)
constexpr size_t kOffPvT    = 0;
constexpr size_t kSzPvT     = (size_t)kPvElems * 4;          // 4,325,376
constexpr size_t kOffVox    = kOffPvT + kSzPvT;
constexpr size_t kSzVox     = (size_t)kPts * 4;              // 2,770,944
constexpr size_t kOffWgt    = kOffVox + kSzVox;
constexpr size_t kSzWgt     = (size_t)kPts * 4;
constexpr size_t kOffCnt    = kOffWgt + kSzWgt;              // 16B aligned
constexpr size_t kSzCnt     = (size_t)kVox * 4;              // 640,000
constexpr size_t kOffOffs   = kOffCnt + kSzCnt;
constexpr size_t kSzOffs    = 640256;                        // padded
constexpr size_t kOffBSum   = kOffOffs + kSzOffs;
constexpr size_t kSzBSum    = 2560;                          // 625 u32, padded
constexpr size_t kOffSKW    = kOffBSum + kSzBSum;
constexpr size_t kSzSKW     = (size_t)kPts * 8;              // uint2 (pix, wgt-bits)
constexpr size_t kWsNeed    = kOffSKW + kSzSKW + 256;        // ~16.7 MB

constexpr int kZeroVec4 = (int)(kSzCnt / 16);                // 40000 uint4 stores
constexpr int kZeroBlks = (kZeroVec4 + 255) / 256;           // 157
}

__device__ __forceinline__ void inv3x3(const float m[9], float inv[9]) {
    float a = m[0], b = m[1], c = m[2];
    float d = m[3], e = m[4], f = m[5];
    float g = m[6], h = m[7], i = m[8];
    float A =  (e * i - f * h);
    float Bm = -(d * i - f * g);
    float Cm =  (d * h - e * g);
    float det = a * A + b * Bm + c * Cm;
    float r = 1.0f / det;
    inv[0] = A * r;
    inv[1] = -(b * i - c * h) * r;
    inv[2] =  (b * f - c * e) * r;
    inv[3] = Bm * r;
    inv[4] =  (a * i - c * g) * r;
    inv[5] = -(a * f - c * d) * r;
    inv[6] = Cm * r;
    inv[7] = -(a * h - b * g) * r;
    inv[8] =  (a * e - b * d) * r;
}

// compute per-camera derived matrices for bn into LDS slots
__device__ __forceinline__ void camera_mats(int bn,
                                            const float* __restrict__ rots,
                                            const float* __restrict__ trans,
                                            const float* __restrict__ intrins,
                                            const float* __restrict__ post_rots,
                                            const float* __restrict__ post_trans,
                                            float* sM, float* sPR, float* sPT, float* sT) {
    float Km[9], PRm[9], invK[9], invPR[9];
#pragma unroll
    for (int i = 0; i < 9; ++i) { Km[i] = intrins[bn * 9 + i]; PRm[i] = post_rots[bn * 9 + i]; }
    inv3x3(Km, invK);
    inv3x3(PRm, invPR);
    const float* R = rots + bn * 9;
#pragma unroll
    for (int i = 0; i < 3; ++i)
#pragma unroll
        for (int j = 0; j < 3; ++j)
            sM[i * 3 + j] = R[i * 3 + 0] * invK[0 * 3 + j]
                          + R[i * 3 + 1] * invK[1 * 3 + j]
                          + R[i * 3 + 2] * invK[2 * 3 + j];
#pragma unroll
    for (int i = 0; i < 9; ++i) sPR[i] = invPR[i];
#pragma unroll
    for (int i = 0; i < 3; ++i) { sPT[i] = post_trans[bn * 3 + i]; sT[i] = trans[bn * 3 + i]; }
}

// full geometry for point q (used by fallback only)
__device__ __forceinline__ int geo_flat(int q,
                                        const float* __restrict__ rots,
                                        const float* __restrict__ trans,
                                        const float* __restrict__ intrins,
                                        const float* __restrict__ post_rots,
                                        const float* __restrict__ post_trans) {
    const int bn  = q / (kD * kHW);
    const int rem = q - bn * (kD * kHW);
    const int d   = rem / kHW;
    const int hw  = rem - d * kHW;
    const int h   = hw / kFW;
    const int w   = hw - h * kFW;
    const int b   = bn / kN;

    float M[9], PR[9], PT[3], T[3];
    camera_mats(bn, rots, trans, intrins, post_rots, post_trans, M, PR, PT, T);

    const float u  = (float)w * (703.0f / 43.0f);
    const float v  = (float)h * 17.0f;
    const float dv = 4.0f + (float)d;
    const float px = u - PT[0], py = v - PT[1], pz = dv - PT[2];
    const float ax = PR[0] * px + PR[1] * py + PR[2] * pz;
    const float ay = PR[3] * px + PR[4] * py + PR[5] * pz;
    const float az = PR[6] * px + PR[7] * py + PR[8] * pz;
    const float qx = ax * az, qy = ay * az, qz = az;
    const float gx = M[0] * qx + M[1] * qy + M[2] * qz + T[0];
    const float gy = M[3] * qx + M[4] * qy + M[5] * qz + T[1];
    const float gz = M[6] * qx + M[7] * qy + M[8] * qz + T[2];
    const float fx = (gx + 50.0f) / 0.5f;
    const float fy = (gy + 50.0f) / 0.5f;
    const float fz = (gz + 10.0f) / 20.0f;
    const int gix = (int)fx;
    const int giy = (int)fy;
    const int giz = (int)fz;
    if (gix >= 0 && gix < kNX0 && giy >= 0 && giy < kNX1 && giz == 0)
        return (b * kNX0 + gix) * kNX1 + giy;
    return -1;
}

// ---- K-1 "zero": fast coalesced zero of counts ----
__global__ __launch_bounds__(256) void lss_zero(uint4* __restrict__ dst) {
    const int i = blockIdx.x * 256 + threadIdx.x;
    if (i < kZeroVec4) dst[i] = make_uint4(0u, 0u, 0u, 0u);
}

// ---- K0 "front": pvT transpose || per-pixel softmax || per-point geometry.
//      Geo branch: a block touches at most TWO cameras (28864 % 256 != 0);
//      both matrix sets hoisted to LDS, threads select by own bn. ----
__global__ __launch_bounds__(256) void lss_front(
    const float* __restrict__ pv,
    const float* __restrict__ feat_depth,
    const float* __restrict__ rots,
    const float* __restrict__ trans,
    const float* __restrict__ intrins,
    const float* __restrict__ post_rots,
    const float* __restrict__ post_trans,
    float* __restrict__ pvT,
    float* __restrict__ wgtArr,
    int* __restrict__ voxArr,
    unsigned* __restrict__ counts)
{
    __shared__ float t[64][65];
    __shared__ float sM[2][9], sPR[2][9], sPT[2][3], sT[2][3];
    const int blk = blockIdx.x;
    const int tid = threadIdx.x;

    if (blk < kPvtTiles) {
        // 64pix x 64c LDS transpose; both sides coalesced
        const int pix0 = blk * 64;
        const int bn  = pix0 / kHW;
        const int hw0 = pix0 - bn * kHW;
        const int lane = tid & 63;
        const int wv   = tid >> 6;
        const float* src = pv + (size_t)(bn * kC) * kHW + hw0;
#pragma unroll
        for (int cc = 0; cc < 16; ++cc) {
            const int c = wv * 16 + cc;
            t[c][lane] = src[(size_t)c * kHW + lane];
        }
        __syncthreads();
        float* dst = pvT + (size_t)pix0 * kC;
#pragma unroll
        for (int jj = 0; jj < 16; ++jj) {
            const int j = wv * 16 + jj;
            dst[j * kC + lane] = t[lane][j];
        }
    } else if (blk < kPvtTiles + kSmBlks) {
        // one THREAD per pixel; softmax fully in registers
        const int pix = (blk - kPvtTiles) * 256 + tid;
        const int bn = pix / kHW;
        const int hw = pix - bn * kHW;
        const float* p = feat_depth + (size_t)(bn * kD) * kHW + hw;
        float v[kD];
#pragma unroll
        for (int d = 0; d < kD; ++d) v[d] = p[(size_t)d * kHW];
        float mx = v[0];
#pragma unroll
        for (int d = 1; d < kD; ++d) mx = fmaxf(mx, v[d]);
        float sm = 0.0f;
#pragma unroll
        for (int d = 0; d < kD; ++d) { v[d] = __expf(v[d] - mx); sm += v[d]; }
        const float inv = 1.0f / sm;
        float* o = wgtArr + (size_t)(bn * kD) * kHW + hw;
#pragma unroll
        for (int d = 0; d < kD; ++d) o[(size_t)d * kHW] = v[d] * inv;
    } else {
        // per-POINT geometry -> voxArr + histogram; <=2 cameras per block
        const int q0  = (blk - kPvtTiles - kSmBlks) * 256;      // 2706 blocks exact
        const int q   = q0 + tid;
        const int bn0 = q0 / (kD * kHW);
        const int bn1 = (q0 + 255) / (kD * kHW);                // bn0 or bn0+1
        if (tid == 0)
            camera_mats(bn0, rots, trans, intrins, post_rots, post_trans,
                        sM[0], sPR[0], sPT[0], sT[0]);
        if (tid == 64 && bn1 != bn0)
            camera_mats(bn1, rots, trans, intrins, post_rots, post_trans,
                        sM[1], sPR[1], sPT[1], sT[1]);
        __syncthreads();

        const int bn  = q / (kD * kHW);
        const int s   = (bn != bn0) ? 1 : 0;
        const int rem = q - bn * (kD * kHW);
        const int d   = rem / kHW;
        const int hw  = rem - d * kHW;
        const int h   = hw / kFW;
        const int w   = hw - h * kFW;
        const int b   = bn / kN;
        const float u  = (float)w * (703.0f / 43.0f);
        const float v  = (float)h * 17.0f;
        const float dv = 4.0f + (float)d;
        const float px = u - sPT[s][0], py = v - sPT[s][1], pz = dv - sPT[s][2];
        const float ax = sPR[s][0] * px + sPR[s][1] * py + sPR[s][2] * pz;
        const float ay = sPR[s][3] * px + sPR[s][4] * py + sPR[s][5] * pz;
        const float az = sPR[s][6] * px + sPR[s][7] * py + sPR[s][8] * pz;
        const float qx = ax * az, qy = ay * az, qz = az;
        const float gx = sM[s][0] * qx + sM[s][1] * qy + sM[s][2] * qz + sT[s][0];
        const float gy = sM[s][3] * qx + sM[s][4] * qy + sM[s][5] * qz + sT[s][1];
        const float gz = sM[s][6] * qx + sM[s][7] * qy + sM[s][8] * qz + sT[s][2];
        const float fx = (gx + 50.0f) / 0.5f;
        const float fy = (gy + 50.0f) / 0.5f;
        const float fz = (gz + 10.0f) / 20.0f;
        const int gix = (int)fx;
        const int giy = (int)fy;
        const int giz = (int)fz;
        int f = -1;
        if (gix >= 0 && gix < kNX0 && giy >= 0 && giy < kNX1 && giz == 0) {
            f = (b * kNX0 + gix) * kNX1 + giy;
            atomicAdd(&counts[f], 1u);
        }
        voxArr[q] = f;
    }
}

// ---- K1a: block-local exclusive scan (625 x 256); offsets stay BLOCK-LOCAL ----
__global__ __launch_bounds__(256) void lss_scan_a(const unsigned* __restrict__ counts,
                                                  unsigned* __restrict__ offsets,
                                                  unsigned* __restrict__ blockSums) {
    const int i = blockIdx.x * 256 + threadIdx.x;
    const int lane = threadIdx.x & 63;
    const int wv = threadIdx.x >> 6;
    const unsigned c = counts[i];
    unsigned s = c;
#pragma unroll
    for (int o = 1; o < 64; o <<= 1) {
        unsigned v = __shfl_up(s, o);
        if (lane >= o) s += v;
    }
    __shared__ unsigned wsum[4];
    if (lane == 63) wsum[wv] = s;
    __syncthreads();
    unsigned base = 0;
#pragma unroll
    for (int k = 0; k < 3; ++k)
        if (k < wv) base += wsum[k];
    const unsigned incl = s + base;
    offsets[i] = incl - c;                  // block-local exclusive
    if (threadIdx.x == 255) blockSums[blockIdx.x] = incl;
}

// ---- K1b: scan 625 block sums in place -> exclusive block bases ----
__global__ __launch_bounds__(1024) void lss_scan_b(unsigned* __restrict__ blockSums) {
    const int t = threadIdx.x;
    const int lane = t & 63;
    const int wv = t >> 6;
    const unsigned c = (t < kScanBlks) ? blockSums[t] : 0u;
    unsigned s = c;
#pragma unroll
    for (int o = 1; o < 64; o <<= 1) {
        unsigned v = __shfl_up(s, o);
        if (lane >= o) s += v;
    }
    __shared__ unsigned wsum[16];
    if (lane == 63) wsum[wv] = s;
    __syncthreads();
    unsigned base = 0;
#pragma unroll
    for (int k = 0; k < 15; ++k)
        if (k < wv) base += wsum[k];
    if (t < kScanBlks) blockSums[t] = (s + base) - c;   // exclusive base
}

// ---- K2: scatter (pix, wgt) into CSR order; voxArr reloaded.
//      global slot = local cursor + blockSums[f>>8]. ----
__global__ __launch_bounds__(256) void lss_order(const int* __restrict__ voxArr,
                                                 const float* __restrict__ wgtArr,
                                                 unsigned* __restrict__ offsets,
                                                 const unsigned* __restrict__ blockSums,
                                                 uint2* __restrict__ skw) {
    const int q = blockIdx.x * 256 + threadIdx.x;      // 2706 blocks exact
    const int f = voxArr[q];
    if (f >= 0) {
        const unsigned slot = atomicAdd(&offsets[f], 1u) + blockSums[f >> 8];
        const int bn  = q / (kD * kHW);
        const int rem = q - bn * (kD * kHW);
        const int hw  = rem % kHW;
        uint2 u;
        u.x = (unsigned)(bn * kHW + hw);               // pix
        u.y = __float_as_uint(wgtArr[q]);
        skw[slot] = u;
    }
}

// ---- K3: per-tile gather; LDS-staged CSR segment; register accumulate ----
__global__ __launch_bounds__(512) void lss_gather(const float* __restrict__ pvT,
                                                  const unsigned* __restrict__ offsets,
                                                  const unsigned* __restrict__ blockSums,
                                                  const uint2* __restrict__ skw,
                                                  float* __restrict__ out) {
    constexpr int kChunk = 2048;                   // 16 KB staging buffer
    __shared__ float acc[50][65];                  // 13 KB
    __shared__ uint2 sbuf[kChunk];                 // 16 KB
    __shared__ unsigned rowOff[51];
    const int tile = blockIdx.x;                   // b*800 + xi*4 + yt
    const int yt = tile & 3;
    const int xi = (tile >> 2) % kNX0;
    const int b  = tile / (kNX0 * 4);
    const int yi0 = yt * 50;
    const int lane = threadIdx.x & 63;
    const int wave = threadIdx.x >> 6;             // 0..7
    const int flat0 = (b * kNX0 + xi) * kNX1 + yi0;

    for (int e = threadIdx.x; e < 50 * 65; e += 512)
        ((float*)acc)[e] = 0.0f;
    if (threadIdx.x < 51) {
        const int f = flat0 - 1 + (int)threadIdx.x;
        rowOff[threadIdx.x] = (f < 0) ? 0u : (offsets[f] + blockSums[f >> 8]);
    }
    __syncthreads();

    const unsigned seg0 = rowOff[0];
    const unsigned seg1 = rowOff[50];

    for (unsigned cb = seg0; cb < seg1; cb += (unsigned)kChunk) {
        const unsigned ce = min(cb + (unsigned)kChunk, seg1);
        const int n = (int)(ce - cb);
        for (int e = threadIdx.x; e < n; e += 512)
            sbuf[e] = skw[cb + e];
        __syncthreads();

        for (int j = wave; j < 50; j += 8) {
            unsigned s0 = max(rowOff[j], cb);
            unsigned e0 = min(rowOff[j + 1], ce);
            if (s0 >= e0) continue;
            float a0 = 0.0f, a1 = 0.0f, a2 = 0.0f, a3 = 0.0f;
            int p  = (int)(s0 - cb);
            int pe = (int)(e0 - cb);
            for (; p + 8 <= pe; p += 8) {
                const uint2 u0 = sbuf[p + 0];
                const uint2 u1 = sbuf[p + 1];
                const uint2 u2 = sbuf[p + 2];
                const uint2 u3 = sbuf[p + 3];
                const uint2 u4 = sbuf[p + 4];
                const uint2 u5 = sbuf[p + 5];
                const uint2 u6 = sbuf[p + 6];
                const uint2 u7 = sbuf[p + 7];
                const float* r0 = pvT + (size_t)((unsigned)__builtin_amdgcn_readfirstlane(u0.x)) * kC;
                const float* r1 = pvT + (size_t)((unsigned)__builtin_amdgcn_readfirstlane(u1.x)) * kC;
                const float* r2 = pvT + (size_t)((unsigned)__builtin_amdgcn_readfirstlane(u2.x)) * kC;
                const float* r3 = pvT + (size_t)((unsigned)__builtin_amdgcn_readfirstlane(u3.x)) * kC;
                const float* r4 = pvT + (size_t)((unsigned)__builtin_amdgcn_readfirstlane(u4.x)) * kC;
                const float* r5 = pvT + (size_t)((unsigned)__builtin_amdgcn_readfirstlane(u5.x)) * kC;
                const float* r6 = pvT + (size_t)((unsigned)__builtin_amdgcn_readfirstlane(u6.x)) * kC;
                const float* r7 = pvT + (size_t)((unsigned)__builtin_amdgcn_readfirstlane(u7.x)) * kC;
                const float f0 = r0[lane], f1 = r1[lane], f2 = r2[lane], f3 = r3[lane];
                const float f4 = r4[lane], f5 = r5[lane], f6 = r6[lane], f7 = r7[lane];
                a0 = fmaf(__uint_as_float(__builtin_amdgcn_readfirstlane(u0.y)), f0, a0);
                a1 = fmaf(__uint_as_float(__builtin_amdgcn_readfirstlane(u1.y)), f1, a1);
                a2 = fmaf(__uint_as_float(__builtin_amdgcn_readfirstlane(u2.y)), f2, a2);
                a3 = fmaf(__uint_as_float(__builtin_amdgcn_readfirstlane(u3.y)), f3, a3);
                a0 = fmaf(__uint_as_float(__builtin_amdgcn_readfirstlane(u4.y)), f4, a0);
                a1 = fmaf(__uint_as_float(__builtin_amdgcn_readfirstlane(u5.y)), f5, a1);
                a2 = fmaf(__uint_as_float(__builtin_amdgcn_readfirstlane(u6.y)), f6, a2);
                a3 = fmaf(__uint_as_float(__builtin_amdgcn_readfirstlane(u7.y)), f7, a3);
            }
            for (; p < pe; ++p) {
                const uint2 u = sbuf[p];
                const float* r = pvT + (size_t)((unsigned)__builtin_amdgcn_readfirstlane(u.x)) * kC;
                a0 = fmaf(__uint_as_float(__builtin_amdgcn_readfirstlane(u.y)), r[lane], a0);
            }
            acc[j][lane] += (a0 + a1) + (a2 + a3);
        }
        __syncthreads();
    }
    __syncthreads();

    for (int e = threadIdx.x; e < kC * 50; e += 512) {
        const int c = e / 50, j = e % 50;
        out[((b * kC + c) * (kNX0 * kNX1)) + xi * kNX1 + yi0 + j] = acc[j][c];
    }
}

// ---- fallback: atomic path (used only if ws too small) ----
__global__ __launch_bounds__(256) void lss_scatter_fb(
    const float* __restrict__ feat_depth,
    const float* __restrict__ feat_pv,
    const float* __restrict__ rots,
    const float* __restrict__ trans,
    const float* __restrict__ intrins,
    const float* __restrict__ post_rots,
    const float* __restrict__ post_trans,
    float* __restrict__ out)
{
    const int lane = threadIdx.x & 63;
    const int wave = threadIdx.x >> 6;
    const int pix  = blockIdx.x * 4 + wave;
    const int w  = pix % kFW;
    const int h  = (pix / kFW) % kFH;
    const int bn = pix / kHW;
    const int b  = bn / kN;
    const int pixBase = h * kFW + w;
    float fd = -INFINITY;
    if (lane < kD)
        fd = feat_depth[(bn * kD + lane) * kHW + pixBase];
    float mx = fd;
#pragma unroll
    for (int off = 32; off >= 1; off >>= 1)
        mx = fmaxf(mx, __shfl_xor(mx, off));
    float ex = (lane < kD) ? __expf(fd - mx) : 0.0f;
    float sm = ex;
#pragma unroll
    for (int off = 32; off >= 1; off >>= 1)
        sm += __shfl_xor(sm, off);
    const float wgt = ex / sm;
    int vox = -1;
    if (lane < kD) {
        const int q = (bn * kD + lane) * kHW + pixBase;
        const int f = geo_flat(q, rots, trans, intrins, post_rots, post_trans);
        if (f >= 0) vox = f % (kNX0 * kNX1);
    }
    const float fc = feat_pv[(bn * kC + lane) * kHW + pixBase];
    const int outBase = (b * kC + lane) * (kNX0 * kNX1);
#pragma unroll 1
    for (int d = 0; d < kD; ++d) {
        const int   vd = __shfl(vox, d);
        const float wd = __shfl(wgt, d);
        if (vd >= 0)
            atomicAdd(&out[outBase + vd], wd * fc);
    }
}

extern "C" void kernel_launch(void* const* d_in, const int* in_sizes, int n_in,
                              void* d_out, int out_size, void* d_ws, size_t ws_size,
                              hipStream_t stream) {
    const float* feat_depth = (const float*)d_in[0];
    const float* feat_pv    = (const float*)d_in[1];
    const float* rots       = (const float*)d_in[2];
    const float* trans      = (const float*)d_in[3];
    const float* intrins    = (const float*)d_in[4];
    const float* post_rots  = (const float*)d_in[5];
    const float* post_trans = (const float*)d_in[6];
    float* out = (float*)d_out;

    if (ws_size < kWsNeed) {
        hipMemsetAsync(out, 0, (size_t)out_size * sizeof(float), stream);
        lss_scatter_fb<<<kPix / 4, 256, 0, stream>>>(
            feat_depth, feat_pv, rots, trans, intrins, post_rots, post_trans, out);
        return;
    }

    char* ws = (char*)d_ws;
    float*    pvT      = (float*)   (ws + kOffPvT);
    int*      voxArr   = (int*)     (ws + kOffVox);
    float*    wgtArr   = (float*)   (ws + kOffWgt);
    unsigned* counts   = (unsigned*)(ws + kOffCnt);
    unsigned* offsets  = (unsigned*)(ws + kOffOffs);
    unsigned* blockSums= (unsigned*)(ws + kOffBSum);
    uint2*    skw      = (uint2*)   (ws + kOffSKW);

    lss_zero<<<kZeroBlks, 256, 0, stream>>>((uint4*)(ws + kOffCnt));
    lss_front<<<kFrontBlks, 256, 0, stream>>>(
        feat_pv, feat_depth, rots, trans, intrins, post_rots, post_trans,
        pvT, wgtArr, voxArr, counts);
    lss_scan_a<<<kScanBlks, 256, 0, stream>>>(counts, offsets, blockSums);
    lss_scan_b<<<1, 1024, 0, stream>>>(blockSums);
    lss_order<<<kPts / 256, 256, 0, stream>>>(voxArr, wgtArr, offsets, blockSums, skw);
    lss_gather<<<kB * kNX0 * 4, 512, 0, stream>>>(pvT, offsets, blockSums, skw, out);
}

// Round 19
// 107.608 us; speedup vs baseline: 1.3958x; 1.0368x over previous
//
#include <hip/hip_runtime.h>
#include <math.h>

namespace {
constexpr int kB = 4, kN = 6, kC = 64, kD = 41, kFH = 16, kFW = 44;
constexpr int kNX0 = 200, kNX1 = 200;
constexpr int kHW  = kFH * kFW;                    // 704
constexpr int kPix = kB * kN * kHW;                // 16896 pixels
constexpr int kPts = kPix * kD;                    // 692736 points
constexpr int kVox = kB * kNX0 * kNX1;             // 160000 voxels
constexpr int kPvElems = kPix * kC;                // 1081344
constexpr int kScanBlks = kVox / 256;              // 625 (exact)
constexpr int kPvtTiles = kPix / 64;               // 264
constexpr int kSmBlks = kPix / 256;                // 66
constexpr int kGeoBlks = (kPts + 1023) / 1024;     // 677 (4 pts/thread)
constexpr int kFrontBlks = kPvtTiles + kSmBlks + kGeoBlks;   // 1007
constexpr int kOrderBlks = kGeoBlks;               // 677

// ws carve (kOffCnt 16B-aligned)
constexpr size_t kOffPvT    = 0;
constexpr size_t kSzPvT     = (size_t)kPvElems * 4;          // 4,325,376
constexpr size_t kOffVox    = kOffPvT + kSzPvT;
constexpr size_t kSzVox     = (size_t)kPts * 4;              // 2,770,944
constexpr size_t kOffWgt    = kOffVox + kSzVox;
constexpr size_t kSzWgt     = (size_t)kPts * 4;
constexpr size_t kOffCnt    = kOffWgt + kSzWgt;              // 16B aligned
constexpr size_t kSzCnt     = (size_t)kVox * 4;              // 640,000
constexpr size_t kOffOffs   = kOffCnt + kSzCnt;
constexpr size_t kSzOffs    = 640256;                        // padded
constexpr size_t kOffBSum   = kOffOffs + kSzOffs;
constexpr size_t kSzBSum    = 2560;                          // 625 u32, padded
constexpr size_t kOffSKW    = kOffBSum + kSzBSum;
constexpr size_t kSzSKW     = (size_t)kPts * 8;              // uint2 (pix, wgt-bits)
constexpr size_t kWsNeed    = kOffSKW + kSzSKW + 256;        // ~16.7 MB

constexpr int kZeroVec4 = (int)(kSzCnt / 16);                // 40000 uint4 stores
constexpr int kZeroBlks = (kZeroVec4 + 255) / 256;           // 157
}

__device__ __forceinline__ void inv3x3(const float m[9], float inv[9]) {
    float a = m[0], b = m[1], c = m[2];
    float d = m[3], e = m[4], f = m[5];
    float g = m[6], h = m[7], i = m[8];
    float A =  (e * i - f * h);
    float Bm = -(d * i - f * g);
    float Cm =  (d * h - e * g);
    float det = a * A + b * Bm + c * Cm;
    float r = 1.0f / det;
    inv[0] = A * r;
    inv[1] = -(b * i - c * h) * r;
    inv[2] =  (b * f - c * e) * r;
    inv[3] = Bm * r;
    inv[4] =  (a * i - c * g) * r;
    inv[5] = -(a * f - c * d) * r;
    inv[6] = Cm * r;
    inv[7] = -(a * h - b * g) * r;
    inv[8] =  (a * e - b * d) * r;
}

// compute per-camera derived matrices for bn into LDS slots
__device__ __forceinline__ void camera_mats(int bn,
                                            const float* __restrict__ rots,
                                            const float* __restrict__ trans,
                                            const float* __restrict__ intrins,
                                            const float* __restrict__ post_rots,
                                            const float* __restrict__ post_trans,
                                            float* sM, float* sPR, float* sPT, float* sT) {
    float Km[9], PRm[9], invK[9], invPR[9];
#pragma unroll
    for (int i = 0; i < 9; ++i) { Km[i] = intrins[bn * 9 + i]; PRm[i] = post_rots[bn * 9 + i]; }
    inv3x3(Km, invK);
    inv3x3(PRm, invPR);
    const float* R = rots + bn * 9;
#pragma unroll
    for (int i = 0; i < 3; ++i)
#pragma unroll
        for (int j = 0; j < 3; ++j)
            sM[i * 3 + j] = R[i * 3 + 0] * invK[0 * 3 + j]
                          + R[i * 3 + 1] * invK[1 * 3 + j]
                          + R[i * 3 + 2] * invK[2 * 3 + j];
#pragma unroll
    for (int i = 0; i < 9; ++i) sPR[i] = invPR[i];
#pragma unroll
    for (int i = 0; i < 3; ++i) { sPT[i] = post_trans[bn * 3 + i]; sT[i] = trans[bn * 3 + i]; }
}

// full geometry for point q (used by fallback only)
__device__ __forceinline__ int geo_flat(int q,
                                        const float* __restrict__ rots,
                                        const float* __restrict__ trans,
                                        const float* __restrict__ intrins,
                                        const float* __restrict__ post_rots,
                                        const float* __restrict__ post_trans) {
    const int bn  = q / (kD * kHW);
    const int rem = q - bn * (kD * kHW);
    const int d   = rem / kHW;
    const int hw  = rem - d * kHW;
    const int h   = hw / kFW;
    const int w   = hw - h * kFW;
    const int b   = bn / kN;

    float M[9], PR[9], PT[3], T[3];
    camera_mats(bn, rots, trans, intrins, post_rots, post_trans, M, PR, PT, T);

    const float u  = (float)w * (703.0f / 43.0f);
    const float v  = (float)h * 17.0f;
    const float dv = 4.0f + (float)d;
    const float px = u - PT[0], py = v - PT[1], pz = dv - PT[2];
    const float ax = PR[0] * px + PR[1] * py + PR[2] * pz;
    const float ay = PR[3] * px + PR[4] * py + PR[5] * pz;
    const float az = PR[6] * px + PR[7] * py + PR[8] * pz;
    const float qx = ax * az, qy = ay * az, qz = az;
    const float gx = M[0] * qx + M[1] * qy + M[2] * qz + T[0];
    const float gy = M[3] * qx + M[4] * qy + M[5] * qz + T[1];
    const float gz = M[6] * qx + M[7] * qy + M[8] * qz + T[2];
    const float fx = (gx + 50.0f) / 0.5f;
    const float fy = (gy + 50.0f) / 0.5f;
    const float fz = (gz + 10.0f) / 20.0f;
    const int gix = (int)fx;
    const int giy = (int)fy;
    const int giz = (int)fz;
    if (gix >= 0 && gix < kNX0 && giy >= 0 && giy < kNX1 && giz == 0)
        return (b * kNX0 + gix) * kNX1 + giy;
    return -1;
}

// ---- K-1 "zero": fast coalesced zero of counts ----
__global__ __launch_bounds__(256) void lss_zero(uint4* __restrict__ dst) {
    const int i = blockIdx.x * 256 + threadIdx.x;
    if (i < kZeroVec4) dst[i] = make_uint4(0u, 0u, 0u, 0u);
}

// ---- K0 "front": pvT transpose || per-pixel softmax || per-point geometry.
//      Geo branch: 1024 points/block (4 per thread, 4 independent chains);
//      span < 28864 so at most TWO cameras; both matrix sets in LDS. ----
__global__ __launch_bounds__(256) void lss_front(
    const float* __restrict__ pv,
    const float* __restrict__ feat_depth,
    const float* __restrict__ rots,
    const float* __restrict__ trans,
    const float* __restrict__ intrins,
    const float* __restrict__ post_rots,
    const float* __restrict__ post_trans,
    float* __restrict__ pvT,
    float* __restrict__ wgtArr,
    int* __restrict__ voxArr,
    unsigned* __restrict__ counts)
{
    __shared__ float t[64][65];
    __shared__ float sM[2][9], sPR[2][9], sPT[2][3], sT[2][3];
    const int blk = blockIdx.x;
    const int tid = threadIdx.x;

    if (blk < kPvtTiles) {
        // 64pix x 64c LDS transpose; both sides coalesced
        const int pix0 = blk * 64;
        const int bn  = pix0 / kHW;
        const int hw0 = pix0 - bn * kHW;
        const int lane = tid & 63;
        const int wv   = tid >> 6;
        const float* src = pv + (size_t)(bn * kC) * kHW + hw0;
#pragma unroll
        for (int cc = 0; cc < 16; ++cc) {
            const int c = wv * 16 + cc;
            t[c][lane] = src[(size_t)c * kHW + lane];
        }
        __syncthreads();
        float* dst = pvT + (size_t)pix0 * kC;
#pragma unroll
        for (int jj = 0; jj < 16; ++jj) {
            const int j = wv * 16 + jj;
            dst[j * kC + lane] = t[lane][j];
        }
    } else if (blk < kPvtTiles + kSmBlks) {
        // one THREAD per pixel; softmax fully in registers
        const int pix = (blk - kPvtTiles) * 256 + tid;
        const int bn = pix / kHW;
        const int hw = pix - bn * kHW;
        const float* p = feat_depth + (size_t)(bn * kD) * kHW + hw;
        float v[kD];
#pragma unroll
        for (int d = 0; d < kD; ++d) v[d] = p[(size_t)d * kHW];
        float mx = v[0];
#pragma unroll
        for (int d = 1; d < kD; ++d) mx = fmaxf(mx, v[d]);
        float sm = 0.0f;
#pragma unroll
        for (int d = 0; d < kD; ++d) { v[d] = __expf(v[d] - mx); sm += v[d]; }
        const float inv = 1.0f / sm;
        float* o = wgtArr + (size_t)(bn * kD) * kHW + hw;
#pragma unroll
        for (int d = 0; d < kD; ++d) o[(size_t)d * kHW] = v[d] * inv;
    } else {
        // per-POINT geometry, 4 points per thread -> voxArr + histogram
        const int q0  = (blk - kPvtTiles - kSmBlks) * 1024;     // 677 blocks
        const int bn0 = q0 / (kD * kHW);
        const int bn1 = min(q0 + 1023, kPts - 1) / (kD * kHW);  // bn0 or bn0+1
        if (tid == 0)
            camera_mats(bn0, rots, trans, intrins, post_rots, post_trans,
                        sM[0], sPR[0], sPT[0], sT[0]);
        if (tid == 64 && bn1 != bn0)
            camera_mats(bn1, rots, trans, intrins, post_rots, post_trans,
                        sM[1], sPR[1], sPT[1], sT[1]);
        __syncthreads();

#pragma unroll
        for (int k = 0; k < 4; ++k) {
            const int q = q0 + k * 256 + tid;
            if (q >= kPts) continue;
            const int bn  = q / (kD * kHW);
            const int s   = (bn != bn0) ? 1 : 0;
            const int rem = q - bn * (kD * kHW);
            const int d   = rem / kHW;
            const int hw  = rem - d * kHW;
            const int h   = hw / kFW;
            const int w   = hw - h * kFW;
            const int b   = bn / kN;
            const float u  = (float)w * (703.0f / 43.0f);
            const float v  = (float)h * 17.0f;
            const float dv = 4.0f + (float)d;
            const float px = u - sPT[s][0], py = v - sPT[s][1], pz = dv - sPT[s][2];
            const float ax = sPR[s][0] * px + sPR[s][1] * py + sPR[s][2] * pz;
            const float ay = sPR[s][3] * px + sPR[s][4] * py + sPR[s][5] * pz;
            const float az = sPR[s][6] * px + sPR[s][7] * py + sPR[s][8] * pz;
            const float qx = ax * az, qy = ay * az, qz = az;
            const float gx = sM[s][0] * qx + sM[s][1] * qy + sM[s][2] * qz + sT[s][0];
            const float gy = sM[s][3] * qx + sM[s][4] * qy + sM[s][5] * qz + sT[s][1];
            const float gz = sM[s][6] * qx + sM[s][7] * qy + sM[s][8] * qz + sT[s][2];
            const float fx = (gx + 50.0f) / 0.5f;
            const float fy = (gy + 50.0f) / 0.5f;
            const float fz = (gz + 10.0f) / 20.0f;
            const int gix = (int)fx;
            const int giy = (int)fy;
            const int giz = (int)fz;
            int f = -1;
            if (gix >= 0 && gix < kNX0 && giy >= 0 && giy < kNX1 && giz == 0) {
                f = (b * kNX0 + gix) * kNX1 + giy;
                atomicAdd(&counts[f], 1u);
            }
            voxArr[q] = f;
        }
    }
}

// ---- K1a: block-local exclusive scan (625 x 256); offsets stay BLOCK-LOCAL ----
__global__ __launch_bounds__(256) void lss_scan_a(const unsigned* __restrict__ counts,
                                                  unsigned* __restrict__ offsets,
                                                  unsigned* __restrict__ blockSums) {
    const int i = blockIdx.x * 256 + threadIdx.x;
    const int lane = threadIdx.x & 63;
    const int wv = threadIdx.x >> 6;
    const unsigned c = counts[i];
    unsigned s = c;
#pragma unroll
    for (int o = 1; o < 64; o <<= 1) {
        unsigned v = __shfl_up(s, o);
        if (lane >= o) s += v;
    }
    __shared__ unsigned wsum[4];
    if (lane == 63) wsum[wv] = s;
    __syncthreads();
    unsigned base = 0;
#pragma unroll
    for (int k = 0; k < 3; ++k)
        if (k < wv) base += wsum[k];
    const unsigned incl = s + base;
    offsets[i] = incl - c;                  // block-local exclusive
    if (threadIdx.x == 255) blockSums[blockIdx.x] = incl;
}

// ---- K1b: scan 625 block sums in place -> exclusive block bases ----
__global__ __launch_bounds__(1024) void lss_scan_b(unsigned* __restrict__ blockSums) {
    const int t = threadIdx.x;
    const int lane = t & 63;
    const int wv = t >> 6;
    const unsigned c = (t < kScanBlks) ? blockSums[t] : 0u;
    unsigned s = c;
#pragma unroll
    for (int o = 1; o < 64; o <<= 1) {
        unsigned v = __shfl_up(s, o);
        if (lane >= o) s += v;
    }
    __shared__ unsigned wsum[16];
    if (lane == 63) wsum[wv] = s;
    __syncthreads();
    unsigned base = 0;
#pragma unroll
    for (int k = 0; k < 15; ++k)
        if (k < wv) base += wsum[k];
    if (t < kScanBlks) blockSums[t] = (s + base) - c;   // exclusive base
}

// ---- K2: scatter (pix, wgt) into CSR order; 4 points per thread.
//      global slot = local cursor + blockSums[f>>8]. ----
__global__ __launch_bounds__(256) void lss_order(const int* __restrict__ voxArr,
                                                 const float* __restrict__ wgtArr,
                                                 unsigned* __restrict__ offsets,
                                                 const unsigned* __restrict__ blockSums,
                                                 uint2* __restrict__ skw) {
    const int q0 = blockIdx.x * 1024;                  // 677 blocks
#pragma unroll
    for (int k = 0; k < 4; ++k) {
        const int q = q0 + k * 256 + threadIdx.x;
        if (q >= kPts) continue;
        const int f = voxArr[q];
        if (f >= 0) {
            const unsigned slot = atomicAdd(&offsets[f], 1u) + blockSums[f >> 8];
            const int bn  = q / (kD * kHW);
            const int rem = q - bn * (kD * kHW);
            const int hw  = rem % kHW;
            uint2 u;
            u.x = (unsigned)(bn * kHW + hw);           // pix
            u.y = __float_as_uint(wgtArr[q]);
            skw[slot] = u;
        }
    }
}

// ---- K3: per-tile gather; LDS-staged CSR segment; register accumulate ----
__global__ __launch_bounds__(512) void lss_gather(const float* __restrict__ pvT,
                                                  const unsigned* __restrict__ offsets,
                                                  const unsigned* __restrict__ blockSums,
                                                  const uint2* __restrict__ skw,
                                                  float* __restrict__ out) {
    constexpr int kChunk = 2048;                   // 16 KB staging buffer
    __shared__ float acc[50][65];                  // 13 KB
    __shared__ uint2 sbuf[kChunk];                 // 16 KB
    __shared__ unsigned rowOff[51];
    const int tile = blockIdx.x;                   // b*800 + xi*4 + yt
    const int yt = tile & 3;
    const int xi = (tile >> 2) % kNX0;
    const int b  = tile / (kNX0 * 4);
    const int yi0 = yt * 50;
    const int lane = threadIdx.x & 63;
    const int wave = threadIdx.x >> 6;             // 0..7
    const int flat0 = (b * kNX0 + xi) * kNX1 + yi0;

    for (int e = threadIdx.x; e < 50 * 65; e += 512)
        ((float*)acc)[e] = 0.0f;
    if (threadIdx.x < 51) {
        const int f = flat0 - 1 + (int)threadIdx.x;
        rowOff[threadIdx.x] = (f < 0) ? 0u : (offsets[f] + blockSums[f >> 8]);
    }
    __syncthreads();

    const unsigned seg0 = rowOff[0];
    const unsigned seg1 = rowOff[50];

    for (unsigned cb = seg0; cb < seg1; cb += (unsigned)kChunk) {
        const unsigned ce = min(cb + (unsigned)kChunk, seg1);
        const int n = (int)(ce - cb);
        for (int e = threadIdx.x; e < n; e += 512)
            sbuf[e] = skw[cb + e];
        __syncthreads();

        for (int j = wave; j < 50; j += 8) {
            unsigned s0 = max(rowOff[j], cb);
            unsigned e0 = min(rowOff[j + 1], ce);
            if (s0 >= e0) continue;
            float a0 = 0.0f, a1 = 0.0f, a2 = 0.0f, a3 = 0.0f;
            int p  = (int)(s0 - cb);
            int pe = (int)(e0 - cb);
            for (; p + 8 <= pe; p += 8) {
                const uint2 u0 = sbuf[p + 0];
                const uint2 u1 = sbuf[p + 1];
                const uint2 u2 = sbuf[p + 2];
                const uint2 u3 = sbuf[p + 3];
                const uint2 u4 = sbuf[p + 4];
                const uint2 u5 = sbuf[p + 5];
                const uint2 u6 = sbuf[p + 6];
                const uint2 u7 = sbuf[p + 7];
                const float* r0 = pvT + (size_t)((unsigned)__builtin_amdgcn_readfirstlane(u0.x)) * kC;
                const float* r1 = pvT + (size_t)((unsigned)__builtin_amdgcn_readfirstlane(u1.x)) * kC;
                const float* r2 = pvT + (size_t)((unsigned)__builtin_amdgcn_readfirstlane(u2.x)) * kC;
                const float* r3 = pvT + (size_t)((unsigned)__builtin_amdgcn_readfirstlane(u3.x)) * kC;
                const float* r4 = pvT + (size_t)((unsigned)__builtin_amdgcn_readfirstlane(u4.x)) * kC;
                const float* r5 = pvT + (size_t)((unsigned)__builtin_amdgcn_readfirstlane(u5.x)) * kC;
                const float* r6 = pvT + (size_t)((unsigned)__builtin_amdgcn_readfirstlane(u6.x)) * kC;
                const float* r7 = pvT + (size_t)((unsigned)__builtin_amdgcn_readfirstlane(u7.x)) * kC;
                const float f0 = r0[lane], f1 = r1[lane], f2 = r2[lane], f3 = r3[lane];
                const float f4 = r4[lane], f5 = r5[lane], f6 = r6[lane], f7 = r7[lane];
                a0 = fmaf(__uint_as_float(__builtin_amdgcn_readfirstlane(u0.y)), f0, a0);
                a1 = fmaf(__uint_as_float(__builtin_amdgcn_readfirstlane(u1.y)), f1, a1);
                a2 = fmaf(__uint_as_float(__builtin_amdgcn_readfirstlane(u2.y)), f2, a2);
                a3 = fmaf(__uint_as_float(__builtin_amdgcn_readfirstlane(u3.y)), f3, a3);
                a0 = fmaf(__uint_as_float(__builtin_amdgcn_readfirstlane(u4.y)), f4, a0);
                a1 = fmaf(__uint_as_float(__builtin_amdgcn_readfirstlane(u5.y)), f5, a1);
                a2 = fmaf(__uint_as_float(__builtin_amdgcn_readfirstlane(u6.y)), f6, a2);
                a3 = fmaf(__uint_as_float(__builtin_amdgcn_readfirstlane(u7.y)), f7, a3);
            }
            for (; p < pe; ++p) {
                const uint2 u = sbuf[p];
                const float* r = pvT + (size_t)((unsigned)__builtin_amdgcn_readfirstlane(u.x)) * kC;
                a0 = fmaf(__uint_as_float(__builtin_amdgcn_readfirstlane(u.y)), r[lane], a0);
            }
            acc[j][lane] += (a0 + a1) + (a2 + a3);
        }
        __syncthreads();
    }
    __syncthreads();

    for (int e = threadIdx.x; e < kC * 50; e += 512) {
        const int c = e / 50, j = e % 50;
        out[((b * kC + c) * (kNX0 * kNX1)) + xi * kNX1 + yi0 + j] = acc[j][c];
    }
}

// ---- fallback: atomic path (used only if ws too small) ----
__global__ __launch_bounds__(256) void lss_scatter_fb(
    const float* __restrict__ feat_depth,
    const float* __restrict__ feat_pv,
    const float* __restrict__ rots,
    const float* __restrict__ trans,
    const float* __restrict__ intrins,
    const float* __restrict__ post_rots,
    const float* __restrict__ post_trans,
    float* __restrict__ out)
{
    const int lane = threadIdx.x & 63;
    const int wave = threadIdx.x >> 6;
    const int pix  = blockIdx.x * 4 + wave;
    const int w  = pix % kFW;
    const int h  = (pix / kFW) % kFH;
    const int bn = pix / kHW;
    const int b  = bn / kN;
    const int pixBase = h * kFW + w;
    float fd = -INFINITY;
    if (lane < kD)
        fd = feat_depth[(bn * kD + lane) * kHW + pixBase];
    float mx = fd;
#pragma unroll
    for (int off = 32; off >= 1; off >>= 1)
        mx = fmaxf(mx, __shfl_xor(mx, off));
    float ex = (lane < kD) ? __expf(fd - mx) : 0.0f;
    float sm = ex;
#pragma unroll
    for (int off = 32; off >= 1; off >>= 1)
        sm += __shfl_xor(sm, off);
    const float wgt = ex / sm;
    int vox = -1;
    if (lane < kD) {
        const int q = (bn * kD + lane) * kHW + pixBase;
        const int f = geo_flat(q, rots, trans, intrins, post_rots, post_trans);
        if (f >= 0) vox = f % (kNX0 * kNX1);
    }
    const float fc = feat_pv[(bn * kC + lane) * kHW + pixBase];
    const int outBase = (b * kC + lane) * (kNX0 * kNX1);
#pragma unroll 1
    for (int d = 0; d < kD; ++d) {
        const int   vd = __shfl(vox, d);
        const float wd = __shfl(wgt, d);
        if (vd >= 0)
            atomicAdd(&out[outBase + vd], wd * fc);
    }
}

extern "C" void kernel_launch(void* const* d_in, const int* in_sizes, int n_in,
                              void* d_out, int out_size, void* d_ws, size_t ws_size,
                              hipStream_t stream) {
    const float* feat_depth = (const float*)d_in[0];
    const float* feat_pv    = (const float*)d_in[1];
    const float* rots       = (const float*)d_in[2];
    const float* trans      = (const float*)d_in[3];
    const float* intrins    = (const float*)d_in[4];
    const float* post_rots  = (const float*)d_in[5];
    const float* post_trans = (const float*)d_in[6];
    float* out = (float*)d_out;

    if (ws_size < kWsNeed) {
        hipMemsetAsync(out, 0, (size_t)out_size * sizeof(float), stream);
        lss_scatter_fb<<<kPix / 4, 256, 0, stream>>>(
            feat_depth, feat_pv, rots, trans, intrins, post_rots, post_trans, out);
        return;
    }

    char* ws = (char*)d_ws;
    float*    pvT      = (float*)   (ws + kOffPvT);
    int*      voxArr   = (int*)     (ws + kOffVox);
    float*    wgtArr   = (float*)   (ws + kOffWgt);
    unsigned* counts   = (unsigned*)(ws + kOffCnt);
    unsigned* offsets  = (unsigned*)(ws + kOffOffs);
    unsigned* blockSums= (unsigned*)(ws + kOffBSum);
    uint2*    skw      = (uint2*)   (ws + kOffSKW);

    lss_zero<<<kZeroBlks, 256, 0, stream>>>((uint4*)(ws + kOffCnt));
    lss_front<<<kFrontBlks, 256, 0, stream>>>(
        feat_pv, feat_depth, rots, trans, intrins, post_rots, post_trans,
        pvT, wgtArr, voxArr, counts);
    lss_scan_a<<<kScanBlks, 256, 0, stream>>>(counts, offsets, blockSums);
    lss_scan_b<<<1, 1024, 0, stream>>>(blockSums);
    lss_order<<<kOrderBlks, 256, 0, stream>>>(voxArr, wgtArr, offsets, blockSums, skw);
    lss_gather<<<kB * kNX0 * 4, 512, 0, stream>>>(pvT, offsets, blockSums, skw, out);
}